// Round 2
// baseline (85.346 us; speedup 1.0000x reference)
//
#include <hip/hip_runtime.h>
#include <hip/hip_fp16.h>
#include <hip/hip_cooperative_groups.h>
#include <cstdint>
#include <cstddef>

namespace cg = cooperative_groups;

#define BATCH 8
#define NPTS  2048
#define CH1   64
#define CH2   128
#define NSAMP 64

typedef _Float16 half8v  __attribute__((ext_vector_type(8)));
typedef _Float16 half2v  __attribute__((ext_vector_type(2)));
typedef float    float4v __attribute__((ext_vector_type(4)));
typedef unsigned uint4v  __attribute__((ext_vector_type(4)));

// packed f16 max, compiler-visible (lowers to v_pk_max_f16)
__device__ inline unsigned pmax(unsigned a, unsigned b) {
  half2v ha = __builtin_bit_cast(half2v, a);
  half2v hb = __builtin_bit_cast(half2v, b);
  return __builtin_bit_cast(unsigned, __builtin_elementwise_max(ha, hb));
}

__device__ inline uint4v pk4max(uint4v a, uint4v b) {
  uint4v d;
#pragma unroll
  for (int i = 0; i < 4; ++i) d[i] = pmax(a[i], b[i]);
  return d;
}

__device__ inline float h2lo(unsigned u) {
  return (float)__builtin_bit_cast(half2v, u)[0];
}
__device__ inline float h2hi(unsigned u) {
  return (float)__builtin_bit_cast(half2v, u)[1];
}

// ---------------------------------------------------------------------------
// MLP part: one block handles 16 points (pbase..pbase+15).
//  wave 0/1 = output half mh, waves 2 (lanes<16) emit xyzq, wave 3 idle.
//  W1/b1 preload vectorized (8 vector loads vs 64 scalar) and consumed
//  group-wise so no 64-reg w1 arrays stay live.
// ---------------------------------------------------------------------------
__device__ inline void mlp_part(const int bid, const int t,
    const float* __restrict__ x,  const float* __restrict__ W1,
    const float* __restrict__ b1, const float* __restrict__ W2,
    const float* __restrict__ b2, __half* __restrict__ h2,
    float4v* __restrict__ xyzq) {
  const int wave = t >> 6;
  const int lane = t & 63;
  const int pbase = (bid & 7) * NPTS + (bid >> 3) * 16;

  if (wave >= 2) {
    if (wave == 2 && lane < 16) {
      const int pt = pbase + lane;
      const float X = x[pt * 3 + 0];
      const float Y = x[pt * 3 + 1];
      const float Z = x[pt * 3 + 2];
      float4v v;
      v[0] = X; v[1] = Y; v[2] = Z; v[3] = fmaf(Z, Z, fmaf(Y, Y, X * X));
      xyzq[pt] = v;
    }
    return;
  }

  const int mh = wave;           // output half: channels mh*64..mh*64+63
  const int n = lane & 15;       // point within group
  const int quad = lane >> 4;    // k-quad
  const int pt = pbase + n;
  const float X = x[pt * 3 + 0];
  const float Y = x[pt * 3 + 1];
  const float Z = x[pt * 3 + 2];

  // h1 fragments: bf0 = channels quad*8..+7, bf1 = channels 32+quad*8..+7
  half8v bf0, bf1;
  {
    float wb[24], bb[8];
#pragma unroll
    for (int i = 0; i < 6; ++i)
      ((float4v*)wb)[i] = ((const float4v*)(W1 + quad * 24))[i];
    ((float4v*)bb)[0] = ((const float4v*)(b1 + quad * 8))[0];
    ((float4v*)bb)[1] = ((const float4v*)(b1 + quad * 8))[1];
#pragma unroll
    for (int j = 0; j < 8; ++j)
      bf0[j] = (_Float16)fmaxf(
          fmaf(wb[3 * j + 2], Z, fmaf(wb[3 * j + 1], Y, fmaf(wb[3 * j], X, bb[j]))), 0.f);
#pragma unroll
    for (int i = 0; i < 6; ++i)
      ((float4v*)wb)[i] = ((const float4v*)(W1 + 96 + quad * 24))[i];
    ((float4v*)bb)[0] = ((const float4v*)(b1 + 32 + quad * 8))[0];
    ((float4v*)bb)[1] = ((const float4v*)(b1 + 32 + quad * 8))[1];
#pragma unroll
    for (int j = 0; j < 8; ++j)
      bf1[j] = (_Float16)fmaxf(
          fmaf(wb[3 * j + 2], Z, fmaf(wb[3 * j + 1], Y, fmaf(wb[3 * j], X, bb[j]))), 0.f);
  }

  half8v afrag[4][2];
  float4v bias[4];
#pragma unroll
  for (int mt = 0; mt < 4; ++mt) {
    const int mtg = mh * 4 + mt;
    const int m = mtg * 16 + n;
#pragma unroll
    for (int kf = 0; kf < 2; ++kf) {
      const float4v* wp = (const float4v*)(W2 + m * CH1 + kf * 32 + quad * 8);
      const float4v lo = wp[0];
      const float4v hi = wp[1];
#pragma unroll
      for (int e = 0; e < 4; ++e) {
        afrag[mt][kf][e]     = (_Float16)lo[e];
        afrag[mt][kf][4 + e] = (_Float16)hi[e];
      }
    }
    bias[mt] = *(const float4v*)(b2 + mtg * 16 + quad * 4);
  }

  __half* hrow = h2 + (size_t)pt * CH2;
#pragma unroll
  for (int mt = 0; mt < 4; ++mt) {
    const int mtg = mh * 4 + mt;
    float4v acc = bias[mt];
    acc = __builtin_amdgcn_mfma_f32_16x16x32_f16(afrag[mt][0], bf0, acc, 0, 0, 0);
    acc = __builtin_amdgcn_mfma_f32_16x16x32_f16(afrag[mt][1], bf1, acc, 0, 0, 0);
    const int p0 = mtg * 16 + quad * 4;
    half2v lo2, hi2;
    lo2[0] = (_Float16)fmaxf(acc[0], 0.f);
    lo2[1] = (_Float16)fmaxf(acc[1], 0.f);
    hi2[0] = (_Float16)fmaxf(acc[2], 0.f);
    hi2[1] = (_Float16)fmaxf(acc[3], 0.f);
    uint2 pk;
    pk.x = __builtin_bit_cast(unsigned, lo2);
    pk.y = __builtin_bit_cast(unsigned, hi2);
    *(uint2*)(hrow + p0) = pk;
  }
}

// ---------------------------------------------------------------------------
// Query part: one block = 16 queries, one WAVE = 4 consecutive queries
// (sequential). Zero __syncthreads: per-wave LDS list + per-wave hfrag
// transpose, wave-local lgkmcnt ordering only. Part B is exactly one
// scheduling round (4096 waves = 4/SIMD all-resident).
// ---------------------------------------------------------------------------
__device__ inline void query_part(const int bid, const int t,
    const float4v* __restrict__ xyzq, const __half* __restrict__ h2,
    float* __restrict__ out, int (&list)[4][NSAMP],
    uint4v (&hfrag)[4][4][16]) {
  const int wave = t >> 6;
  const int lane = t & 63;
  const int b = bid & 7;                       // XCD id owns batch b
  const int s0 = (bid >> 3) * 16 + wave * 4;   // 4 consecutive queries
  const float4v* xq = xyzq + (size_t)b * NPTS;
  const __half* hb = h2 + (size_t)b * NPTS * CH2;
  const unsigned long long lt = (1ull << lane) - 1ull;
  const int csl = lane & 15;
  const int rgrp = lane >> 4;

#pragma unroll 1
  for (int j = 0; j < 4; ++j) {
    const int s = s0 + j;
    const float4v qv = xq[s];
    const float qx = qv[0], qy = qv[1], qz = qv[2], dqf = qv[3];
    const double dq = (double)qx * qx + (double)qy * qy + (double)qz * qz;

    // ---- Phase 1: first NSAMP in-radius hits (ascending), 128/iter ----
    int count = 0;
    int first = 0;
    for (int base = 0; base < NPTS && count < NSAMP; base += 128) {
      const float4v pv0 = xq[base + lane];
      const float4v pv1 = xq[base + 64 + lane];

      const float px0 = pv0[0], py0 = pv0[1], pz0 = pv0[2];
      const float dot0 = fmaf(qz, pz0, fmaf(qy, py0, qx * px0));
      const float dist0 = fmaf(-2.f, dot0, dqf + pv0[3]);
      bool hit0;
      if (__ballot(__builtin_fabsf(dist0 - 0.36f) <= 3e-5f)) {
        // rare exact path: fp64, same evaluation as the np reference
        const double dm = (double)px0 * px0 + (double)py0 * py0 + (double)pz0 * pz0;
        const double dd = (double)qx * px0 + (double)qy * py0 + (double)qz * pz0;
        hit0 = !((dq + dm - 2.0 * dd) > 0.36);
      } else {
        hit0 = !(dist0 > 0.36f);
      }

      const float px1 = pv1[0], py1 = pv1[1], pz1 = pv1[2];
      const float dot1 = fmaf(qz, pz1, fmaf(qy, py1, qx * px1));
      const float dist1 = fmaf(-2.f, dot1, dqf + pv1[3]);
      bool hit1;
      if (__ballot(__builtin_fabsf(dist1 - 0.36f) <= 3e-5f)) {
        const double dm = (double)px1 * px1 + (double)py1 * py1 + (double)pz1 * pz1;
        const double dd = (double)qx * px1 + (double)qy * py1 + (double)qz * pz1;
        hit1 = !((dq + dm - 2.0 * dd) > 0.36);
      } else {
        hit1 = !(dist1 > 0.36f);
      }

      const unsigned long long m0 = __ballot(hit0);
      const unsigned long long m1 = __ballot(hit1);
      const int c0 = __popcll(m0);
      const int c1 = __popcll(m1);

      if (count == 0) {
        first = m0 ? (base + (int)__builtin_ctzll(m0))
                   : (m1 ? (base + 64 + (int)__builtin_ctzll(m1)) : first);
      }
      if (hit0) {
        const int pos = count + __popcll(m0 & lt);
        if (pos < NSAMP) list[wave][pos] = base + lane;
      }
      if (hit1) {
        const int pos = count + c0 + __popcll(m1 & lt);
        if (pos < NSAMP) list[wave][pos] = base + 64 + lane;
      }
      count += c0 + c1;
    }
    // tail fill with first hit (self guarantees count >= 1 on full scan)
    if (count < NSAMP && lane >= count) list[wave][lane] = first;

    asm volatile("s_waitcnt lgkmcnt(0)" ::: "memory");
    __builtin_amdgcn_wave_barrier();

    // ---- Phase 2: lane gathers rows rgrp*16..+15, 16-B slice csl ----
    unsigned off[16];
#pragma unroll
    for (int k = 0; k < 4; ++k) {
      const int4 li = *(const int4*)&list[wave][rgrp * 16 + k * 4];
      off[4 * k + 0] = (unsigned)(li.x * 256 + csl * 16);
      off[4 * k + 1] = (unsigned)(li.y * 256 + csl * 16);
      off[4 * k + 2] = (unsigned)(li.z * 256 + csl * 16);
      off[4 * k + 3] = (unsigned)(li.w * 256 + csl * 16);
    }

    uint4v acc;
    {
      uint4v v[8];
#pragma unroll
      for (int k = 0; k < 8; ++k)
        v[k] = *(const uint4v*)((const char*)hb + (size_t)off[k]);
      uint4v a0 = pk4max(pk4max(v[0], v[1]), pk4max(v[2], v[3]));
      uint4v a1 = pk4max(pk4max(v[4], v[5]), pk4max(v[6], v[7]));
      acc = pk4max(a0, a1);
    }
    {
      uint4v v[8];
#pragma unroll
      for (int k = 0; k < 8; ++k)
        v[k] = *(const uint4v*)((const char*)hb + (size_t)off[8 + k]);
      uint4v a0 = pk4max(pk4max(v[0], v[1]), pk4max(v[2], v[3]));
      uint4v a1 = pk4max(pk4max(v[4], v[5]), pk4max(v[6], v[7]));
      acc = pk4max(acc, pk4max(a0, a1));
    }

    // cross-lane: combine the 4 row-groups
    uint4v o;
#pragma unroll
    for (int i = 0; i < 4; ++i)
      o[i] = (unsigned)__shfl_xor((int)acc[i], 16, 64);
    acc = pk4max(acc, o);
#pragma unroll
    for (int i = 0; i < 4; ++i)
      o[i] = (unsigned)__shfl_xor((int)acc[i], 32, 64);
    acc = pk4max(acc, o);

    if (rgrp == 0) hfrag[wave][j][csl] = acc;
  }

  asm volatile("s_waitcnt lgkmcnt(0)" ::: "memory");
  __builtin_amdgcn_wave_barrier();

  // ---- Epilogue (per-wave, no block barrier): lane owns channels
  //      c = 2*lane, 2*lane+1; dword index within query j is exactly lane.
  //      LDS reads stride-4B (conflict-free), stores are float4 lines. ----
  const unsigned* basep = (const unsigned*)&hfrag[wave][0][0];
  const unsigned d0 = basep[0 * 64 + lane];
  const unsigned d1 = basep[1 * 64 + lane];
  const unsigned d2 = basep[2 * 64 + lane];
  const unsigned d3 = basep[3 * 64 + lane];
  float4v r0, r1;
  r0[0] = h2lo(d0); r0[1] = h2lo(d1); r0[2] = h2lo(d2); r0[3] = h2lo(d3);
  r1[0] = h2hi(d0); r1[1] = h2hi(d1); r1[2] = h2hi(d2); r1[3] = h2hi(d3);
  const size_t ob = (size_t)b * CH2 * NPTS;
  *(float4v*)(out + ob + (size_t)(2 * lane) * NPTS + s0)     = r0;
  *(float4v*)(out + ob + (size_t)(2 * lane + 1) * NPTS + s0) = r1;
}

// ---------------------------------------------------------------------------
// Fused cooperative kernel: 1024 blocks x 256 = 4 blocks/CU co-resident
// (enforced by __launch_bounds__(256,4)). Part A -> grid sync -> part B.
// ---------------------------------------------------------------------------
__global__ __launch_bounds__(256, 4) void fused_kernel(
    const float* __restrict__ x,  const float* __restrict__ W1,
    const float* __restrict__ b1, const float* __restrict__ W2,
    const float* __restrict__ b2, __half* __restrict__ h2,
    float4v* __restrict__ xyzq,   float* __restrict__ out) {
  __shared__ int    list[4][NSAMP];     // 1 KB
  __shared__ uint4v hfrag[4][4][16];    // 4 KB
  const int bid = blockIdx.x;
  const int t = threadIdx.x;
  mlp_part(bid, t, x, W1, b1, W2, b2, h2, xyzq);
  __threadfence();
  cg::this_grid().sync();
  query_part(bid, t, xyzq, h2, out, list, hfrag);
}

// ---- Fallback pair (same improved parts, classic two-dispatch) ----
__global__ __launch_bounds__(256, 4) void mlp16_kernel(
    const float* __restrict__ x,  const float* __restrict__ W1,
    const float* __restrict__ b1, const float* __restrict__ W2,
    const float* __restrict__ b2, __half* __restrict__ h2,
    float4v* __restrict__ xyzq) {
  mlp_part(blockIdx.x, threadIdx.x, x, W1, b1, W2, b2, h2, xyzq);
}

__global__ __launch_bounds__(256, 4) void query16_kernel(
    const float4v* __restrict__ xyzq, const __half* __restrict__ h2,
    float* __restrict__ out) {
  __shared__ int    list[4][NSAMP];
  __shared__ uint4v hfrag[4][4][16];
  query_part(blockIdx.x, threadIdx.x, xyzq, h2, out, list, hfrag);
}

// ---------------------------------------------------------------------------
extern "C" void kernel_launch(void* const* d_in, const int* in_sizes, int n_in,
                              void* d_out, int out_size, void* d_ws, size_t ws_size,
                              hipStream_t stream) {
  const float* x  = (const float*)d_in[0];
  const float* W1 = (const float*)d_in[1];
  const float* b1 = (const float*)d_in[2];
  const float* W2 = (const float*)d_in[3];
  const float* b2 = (const float*)d_in[4];
  float* out = (float*)d_out;

  __half*  h2   = (__half*)d_ws;                                     // 4 MB
  float4v* xyzq = (float4v*)((char*)d_ws + (size_t)4 * 1024 * 1024); // 256 KB

  static int coop_ok = -1;   // -1 unknown, 1 works, 0 rejected
  if (coop_ok != 0) {
    void* args[] = { (void*)&x, (void*)&W1, (void*)&b1, (void*)&W2,
                     (void*)&b2, (void*)&h2, (void*)&xyzq, (void*)&out };
    const hipError_t e = hipLaunchCooperativeKernel(
        reinterpret_cast<void*>(fused_kernel), dim3(1024), dim3(256),
        args, 0, stream);
    if (e == hipSuccess) { coop_ok = 1; return; }
    coop_ok = 0;
    (void)hipGetLastError();   // clear sticky error, fall through
  }

  mlp16_kernel<<<1024, 256, 0, stream>>>(x, W1, b1, W2, b2, h2, xyzq);
  query16_kernel<<<1024, 256, 0, stream>>>(xyzq, h2, out);
}

// Round 3
// 84.251 us; speedup vs baseline: 1.0130x; 1.0130x over previous
//
#include <hip/hip_runtime.h>
#include <hip/hip_fp16.h>
#include <cstdint>
#include <cstddef>

#define BATCH 8
#define NPTS  2048
#define CH1   64
#define CH2   128
#define NSAMP 64

typedef _Float16 half8v  __attribute__((ext_vector_type(8)));
typedef _Float16 half2v  __attribute__((ext_vector_type(2)));
typedef float    float4v __attribute__((ext_vector_type(4)));
typedef unsigned uint4v  __attribute__((ext_vector_type(4)));

// packed f16 max, compiler-visible (lowers to v_pk_max_f16)
__device__ inline unsigned pmax(unsigned a, unsigned b) {
  half2v ha = __builtin_bit_cast(half2v, a);
  half2v hb = __builtin_bit_cast(half2v, b);
  return __builtin_bit_cast(unsigned, __builtin_elementwise_max(ha, hb));
}

__device__ inline uint4v pk4max(uint4v a, uint4v b) {
  uint4v d;
#pragma unroll
  for (int i = 0; i < 4; ++i) d[i] = pmax(a[i], b[i]);
  return d;
}

__device__ inline float h2lo(unsigned u) {
  return (float)__builtin_bit_cast(half2v, u)[0];
}
__device__ inline float h2hi(unsigned u) {
  return (float)__builtin_bit_cast(half2v, u)[1];
}

// ---------------------------------------------------------------------------
// Kernel 1: per-point MLP via MFMA (128 x 16384 x 64 fp16 GEMM). R1 version
// verbatim (proven). Also emits xyzq[pt] = {x,y,z,|p|^2}.
// ---------------------------------------------------------------------------
__global__ __launch_bounds__(256) void mlp_kernel(
    const float* __restrict__ x,
    const float* __restrict__ W1, const float* __restrict__ b1,
    const float* __restrict__ W2, const float* __restrict__ b2,
    __half* __restrict__ h2, float4v* __restrict__ xyzq) {
  const int t = threadIdx.x;
  const int wave = t >> 6;
  const int lane = t & 63;
  const int n = lane & 15;
  const int quad = lane >> 4;
  const int pti = wave >> 1;
  const int mh  = wave & 1;
  const int base = blockIdx.x * 32;

  if (t < 32) {
    const int pt = base + t;
    const float X = x[pt * 3 + 0];
    const float Y = x[pt * 3 + 1];
    const float Z = x[pt * 3 + 2];
    float4v v;
    v[0] = X; v[1] = Y; v[2] = Z; v[3] = fmaf(Z, Z, fmaf(Y, Y, X * X));
    xyzq[pt] = v;
  }

  float w1x[16], w1y[16], w1z[16], b1v[16];
#pragma unroll
  for (int j = 0; j < 16; ++j) {
    const int o = quad * 8 + (j & 7) + ((j < 8) ? 0 : 32);
    w1x[j] = W1[o * 3 + 0];
    w1y[j] = W1[o * 3 + 1];
    w1z[j] = W1[o * 3 + 2];
    b1v[j] = b1[o];
  }

  half8v afrag[4][2];
  float4v bias[4];
#pragma unroll
  for (int mt = 0; mt < 4; ++mt) {
    const int mtg = mh * 4 + mt;
    const int m = mtg * 16 + n;
#pragma unroll
    for (int kf = 0; kf < 2; ++kf) {
      const float4v* wp = (const float4v*)(W2 + m * CH1 + kf * 32 + quad * 8);
      const float4v lo = wp[0];
      const float4v hi = wp[1];
#pragma unroll
      for (int e = 0; e < 4; ++e) {
        afrag[mt][kf][e]     = (_Float16)lo[e];
        afrag[mt][kf][4 + e] = (_Float16)hi[e];
      }
    }
    bias[mt] = *(const float4v*)(b2 + mtg * 16 + quad * 4);
  }

  const int pt = base + pti * 16 + n;
  const float X = x[pt * 3 + 0];
  const float Y = x[pt * 3 + 1];
  const float Z = x[pt * 3 + 2];
  half8v bf0, bf1;
#pragma unroll
  for (int j = 0; j < 8; ++j) {
    const float ha = fmaxf(fmaf(w1z[j], Z, fmaf(w1y[j], Y, fmaf(w1x[j], X, b1v[j]))), 0.f);
    const float hb = fmaxf(fmaf(w1z[8 + j], Z, fmaf(w1y[8 + j], Y, fmaf(w1x[8 + j], X, b1v[8 + j]))), 0.f);
    bf0[j] = (_Float16)ha;
    bf1[j] = (_Float16)hb;
  }

  __half* hrow = h2 + (size_t)pt * CH2;
#pragma unroll
  for (int mt = 0; mt < 4; ++mt) {
    const int mtg = mh * 4 + mt;
    float4v acc = bias[mt];
    acc = __builtin_amdgcn_mfma_f32_16x16x32_f16(afrag[mt][0], bf0, acc, 0, 0, 0);
    acc = __builtin_amdgcn_mfma_f32_16x16x32_f16(afrag[mt][1], bf1, acc, 0, 0, 0);
    const int p0 = mtg * 16 + quad * 4;
    half2v lo2, hi2;
    lo2[0] = (_Float16)fmaxf(acc[0], 0.f);
    lo2[1] = (_Float16)fmaxf(acc[1], 0.f);
    hi2[0] = (_Float16)fmaxf(acc[2], 0.f);
    hi2[1] = (_Float16)fmaxf(acc[3], 0.f);
    uint2 pk;
    pk.x = __builtin_bit_cast(unsigned, lo2);
    pk.y = __builtin_bit_cast(unsigned, hi2);
    *(uint2*)(hrow + p0) = pk;
  }
}

// ---------------------------------------------------------------------------
// Kernel 2 (R14 = R1 structure + shorter phase-1 critical path):
//  - one WAVE per query, 16384 waves (max TLP — the thing R2 gave away).
//  - opening block: points 0..255 evaluated unconditionally (8 loads issued
//    together, ONE borderline ballot) -> common case needs 1 dependent round
//    instead of 2-3; sparse queries continue at 128/iter with early exit.
//  - list[] holds BYTE offsets (idx<<8): kills 16 v_mul_lo in phase-2 setup.
//  - phase 2 / epilogue: R1 layout (two 8-load bursts, shfl reduce, fout
//    transpose, float4 channel-line stores).
// ---------------------------------------------------------------------------
__global__ __launch_bounds__(256, 4) void query_kernel(
    const float4v* __restrict__ xyzq,
    const __half* __restrict__ h2,
    float* __restrict__ out) {
  __shared__ int  list[4][NSAMP];   // 1 KB, per-wave private
  __shared__ float fout[4][CH2];    // 2 KB, 4-query output transpose

  const int t = threadIdx.x;
  const int wave = t >> 6;
  const int lane = t & 63;
  const int bid = blockIdx.x;
  const int b = bid & 7;                  // XCD-aware swizzle: XCD owns batch
  const int sbase = (bid >> 3) << 2;      // 4 consecutive queries per block
  const int s = sbase + wave;

  const float4v* xq = xyzq + (size_t)b * NPTS;
  const float4v qv = xq[s];
  const float qx = qv[0], qy = qv[1], qz = qv[2], dqf = qv[3];
  const double dq = (double)qx * qx + (double)qy * qy + (double)qz * qz;
  const unsigned long long lt = (1ull << lane) - 1ull;

  int count = 0;
  int first = 0;

  // ---- Phase 1a: opening 256 points, no intermediate exit checks ----
  {
    float4v pv[4];
#pragma unroll
    for (int c = 0; c < 4; ++c) pv[c] = xq[c * 64 + lane];
    bool hit[4];
    bool bd = false;
#pragma unroll
    for (int c = 0; c < 4; ++c) {
      const float dot = fmaf(qz, pv[c][2], fmaf(qy, pv[c][1], qx * pv[c][0]));
      const float dist = fmaf(-2.f, dot, dqf + pv[c][3]);
      hit[c] = !(dist > 0.36f);
      bd = bd || (__builtin_fabsf(dist - 0.36f) <= 3e-5f);
    }
    if (__ballot(bd)) {
      // rare exact path: fp64, same evaluation as the np reference
#pragma unroll
      for (int c = 0; c < 4; ++c) {
        const double px = pv[c][0], py = pv[c][1], pz = pv[c][2];
        const double dm = px * px + py * py + pz * pz;
        const double dd = (double)qx * px + (double)qy * py + (double)qz * pz;
        hit[c] = !((dq + dm - 2.0 * dd) > 0.36);
      }
    }
#pragma unroll
    for (int c = 0; c < 4; ++c) {
      const unsigned long long m = __ballot(hit[c]);
      if (count == 0 && m)
        first = (c * 64 + (int)__builtin_ctzll(m)) << 8;
      if (hit[c]) {
        const int pos = count + __popcll(m & lt);
        if (pos < NSAMP) list[wave][pos] = (c * 64 + lane) << 8;
      }
      count += (int)__popcll(m);
    }
  }

  // ---- Phase 1b: tail, 128/iter with early exit ----
  for (int base = 256; base < NPTS && count < NSAMP; base += 128) {
    const float4v pv0 = xq[base + lane];
    const float4v pv1 = xq[base + 64 + lane];

    const float dot0 = fmaf(qz, pv0[2], fmaf(qy, pv0[1], qx * pv0[0]));
    const float dist0 = fmaf(-2.f, dot0, dqf + pv0[3]);
    const float dot1 = fmaf(qz, pv1[2], fmaf(qy, pv1[1], qx * pv1[0]));
    const float dist1 = fmaf(-2.f, dot1, dqf + pv1[3]);
    bool hit0 = !(dist0 > 0.36f);
    bool hit1 = !(dist1 > 0.36f);
    const bool bd = (__builtin_fabsf(dist0 - 0.36f) <= 3e-5f) ||
                    (__builtin_fabsf(dist1 - 0.36f) <= 3e-5f);
    if (__ballot(bd)) {
      {
        const double px = pv0[0], py = pv0[1], pz = pv0[2];
        const double dm = px * px + py * py + pz * pz;
        const double dd = (double)qx * px + (double)qy * py + (double)qz * pz;
        hit0 = !((dq + dm - 2.0 * dd) > 0.36);
      }
      {
        const double px = pv1[0], py = pv1[1], pz = pv1[2];
        const double dm = px * px + py * py + pz * pz;
        const double dd = (double)qx * px + (double)qy * py + (double)qz * pz;
        hit1 = !((dq + dm - 2.0 * dd) > 0.36);
      }
    }

    const unsigned long long m0 = __ballot(hit0);
    const unsigned long long m1 = __ballot(hit1);
    const int c0 = __popcll(m0);
    const int c1 = __popcll(m1);

    if (count == 0) {
      first = m0 ? ((base + (int)__builtin_ctzll(m0)) << 8)
                 : (m1 ? ((base + 64 + (int)__builtin_ctzll(m1)) << 8) : first);
    }
    if (hit0) {
      const int pos = count + __popcll(m0 & lt);
      if (pos < NSAMP) list[wave][pos] = (base + lane) << 8;
    }
    if (hit1) {
      const int pos = count + c0 + __popcll(m1 & lt);
      if (pos < NSAMP) list[wave][pos] = (base + 64 + lane) << 8;
    }
    count += c0 + c1;
  }
  // tail fill with first hit (self guarantees count >= 1 on full scan)
  if (count < NSAMP && lane >= count) list[wave][lane] = first;

  __builtin_amdgcn_wave_barrier();
  asm volatile("s_waitcnt lgkmcnt(0)" ::: "memory");
  __builtin_amdgcn_wave_barrier();

  // ---- Phase 2: lane = (rgrp, csl); gather rows rgrp*16..+15, 16-B slice
  //      csl; in-register max tree, then 2 shfl_xor rounds ----
  const int csl  = lane & 15;
  const int rgrp = lane >> 4;
  const char* hb = (const char*)(h2 + (size_t)b * NPTS * CH2) + csl * 16;

  unsigned off[16];
#pragma unroll
  for (int k = 0; k < 4; ++k) {
    const int4 li = *(const int4*)&list[wave][rgrp * 16 + k * 4];
    off[4 * k + 0] = (unsigned)li.x;
    off[4 * k + 1] = (unsigned)li.y;
    off[4 * k + 2] = (unsigned)li.z;
    off[4 * k + 3] = (unsigned)li.w;
  }

  uint4v acc;
  {
    uint4v v[8];
#pragma unroll
    for (int k = 0; k < 8; ++k)
      v[k] = *(const uint4v*)(hb + (size_t)off[k]);
    uint4v a0 = pk4max(pk4max(v[0], v[1]), pk4max(v[2], v[3]));
    uint4v a1 = pk4max(pk4max(v[4], v[5]), pk4max(v[6], v[7]));
    acc = pk4max(a0, a1);
  }
  {
    uint4v v[8];
#pragma unroll
    for (int k = 0; k < 8; ++k)
      v[k] = *(const uint4v*)(hb + (size_t)off[8 + k]);
    uint4v a0 = pk4max(pk4max(v[0], v[1]), pk4max(v[2], v[3]));
    uint4v a1 = pk4max(pk4max(v[4], v[5]), pk4max(v[6], v[7]));
    acc = pk4max(acc, pk4max(a0, a1));
  }

  // cross-lane: combine the 4 row-groups (lanes csl, csl+16, csl+32, csl+48)
  uint4v o;
#pragma unroll
  for (int i = 0; i < 4; ++i)
    o[i] = (unsigned)__shfl_xor((int)acc[i], 16, 64);
  acc = pk4max(acc, o);
#pragma unroll
  for (int i = 0; i < 4; ++i)
    o[i] = (unsigned)__shfl_xor((int)acc[i], 32, 64);
  acc = pk4max(acc, o);

  // lanes 0..15 hold the final 8-channel slice for this query
  if (rgrp == 0) {
    const int c0 = csl * 8;
    fout[wave][c0 + 0] = h2lo(acc[0]);
    fout[wave][c0 + 1] = h2hi(acc[0]);
    fout[wave][c0 + 2] = h2lo(acc[1]);
    fout[wave][c0 + 3] = h2hi(acc[1]);
    fout[wave][c0 + 4] = h2lo(acc[2]);
    fout[wave][c0 + 5] = h2hi(acc[2]);
    fout[wave][c0 + 6] = h2lo(acc[3]);
    fout[wave][c0 + 7] = h2hi(acc[3]);
  }
  __syncthreads();

  // ---- Epilogue: coalesced float4 write per channel line ----
  if (t < CH2) {
    float4v r;
    r[0] = fout[0][t];
    r[1] = fout[1][t];
    r[2] = fout[2][t];
    r[3] = fout[3][t];
    *(float4v*)(out + ((size_t)b * CH2 + t) * NPTS + sbase) = r;
  }
}

// ---------------------------------------------------------------------------
extern "C" void kernel_launch(void* const* d_in, const int* in_sizes, int n_in,
                              void* d_out, int out_size, void* d_ws, size_t ws_size,
                              hipStream_t stream) {
  const float* x  = (const float*)d_in[0];
  const float* W1 = (const float*)d_in[1];
  const float* b1 = (const float*)d_in[2];
  const float* W2 = (const float*)d_in[3];
  const float* b2 = (const float*)d_in[4];
  float* out = (float*)d_out;

  __half*  h2   = (__half*)d_ws;                                     // 4 MB
  float4v* xyzq = (float4v*)((char*)d_ws + (size_t)4 * 1024 * 1024); // 256 KB

  mlp_kernel<<<(BATCH * NPTS) / 32, 256, 0, stream>>>(
      x, W1, b1, W2, b2, h2, xyzq);
  query_kernel<<<(BATCH * NPTS) / 4, 256, 0, stream>>>(xyzq, h2, out);
}

// Round 4
// 83.168 us; speedup vs baseline: 1.0262x; 1.0130x over previous
//
#include <hip/hip_runtime.h>
#include <hip/hip_fp16.h>
#include <cstdint>
#include <cstddef>

#define BATCH 8
#define NPTS  2048
#define CH1   64
#define CH2   128
#define NSAMP 64

typedef _Float16 half8v  __attribute__((ext_vector_type(8)));
typedef _Float16 half2v  __attribute__((ext_vector_type(2)));
typedef float    float4v __attribute__((ext_vector_type(4)));
typedef unsigned uint4v  __attribute__((ext_vector_type(4)));

// packed f16 max, compiler-visible (lowers to v_pk_max_f16)
__device__ inline unsigned pmax(unsigned a, unsigned b) {
  half2v ha = __builtin_bit_cast(half2v, a);
  half2v hb = __builtin_bit_cast(half2v, b);
  return __builtin_bit_cast(unsigned, __builtin_elementwise_max(ha, hb));
}

__device__ inline uint4v pk4max(uint4v a, uint4v b) {
  uint4v d;
#pragma unroll
  for (int i = 0; i < 4; ++i) d[i] = pmax(a[i], b[i]);
  return d;
}

__device__ inline float h2lo(unsigned u) {
  return (float)__builtin_bit_cast(half2v, u)[0];
}
__device__ inline float h2hi(unsigned u) {
  return (float)__builtin_bit_cast(half2v, u)[1];
}

// ---------------------------------------------------------------------------
// Kernel 1: per-point MLP via MFMA. R1 wave layout (proven: 4 waves, all
// busy, 32 pts/block) + vectorized W1/b1 prologue (16 vector loads instead
// of 64 scalar issue slots per thread). Emits xyzq[pt] = {x,y,z,|p|^2}.
// ---------------------------------------------------------------------------
__global__ __launch_bounds__(256) void mlp_kernel(
    const float* __restrict__ x,
    const float* __restrict__ W1, const float* __restrict__ b1,
    const float* __restrict__ W2, const float* __restrict__ b2,
    __half* __restrict__ h2, float4v* __restrict__ xyzq) {
  const int t = threadIdx.x;
  const int wave = t >> 6;
  const int lane = t & 63;
  const int n = lane & 15;
  const int quad = lane >> 4;
  const int pti = wave >> 1;
  const int mh  = wave & 1;
  const int base = blockIdx.x * 32;

  if (t < 32) {
    const int pt = base + t;
    const float X = x[pt * 3 + 0];
    const float Y = x[pt * 3 + 1];
    const float Z = x[pt * 3 + 2];
    float4v v;
    v[0] = X; v[1] = Y; v[2] = Z; v[3] = fmaf(Z, Z, fmaf(Y, Y, X * X));
    xyzq[pt] = v;
  }

  const int pt = base + pti * 16 + n;
  const float X = x[pt * 3 + 0];
  const float Y = x[pt * 3 + 1];
  const float Z = x[pt * 3 + 2];

  // h1 fragments: bf0 = channels quad*8..+7, bf1 = channels 32+quad*8..+7.
  // W1 rows for this quad are contiguous: 24 floats = 6 float4 per group.
  half8v bf0, bf1;
  {
    float wb[24], bb[8];
#pragma unroll
    for (int i = 0; i < 6; ++i)
      ((float4v*)wb)[i] = ((const float4v*)(W1 + quad * 24))[i];
    ((float4v*)bb)[0] = ((const float4v*)(b1 + quad * 8))[0];
    ((float4v*)bb)[1] = ((const float4v*)(b1 + quad * 8))[1];
#pragma unroll
    for (int j = 0; j < 8; ++j)
      bf0[j] = (_Float16)fmaxf(
          fmaf(wb[3 * j + 2], Z, fmaf(wb[3 * j + 1], Y, fmaf(wb[3 * j], X, bb[j]))), 0.f);
#pragma unroll
    for (int i = 0; i < 6; ++i)
      ((float4v*)wb)[i] = ((const float4v*)(W1 + 96 + quad * 24))[i];
    ((float4v*)bb)[0] = ((const float4v*)(b1 + 32 + quad * 8))[0];
    ((float4v*)bb)[1] = ((const float4v*)(b1 + 32 + quad * 8))[1];
#pragma unroll
    for (int j = 0; j < 8; ++j)
      bf1[j] = (_Float16)fmaxf(
          fmaf(wb[3 * j + 2], Z, fmaf(wb[3 * j + 1], Y, fmaf(wb[3 * j], X, bb[j]))), 0.f);
  }

  half8v afrag[4][2];
  float4v bias[4];
#pragma unroll
  for (int mt = 0; mt < 4; ++mt) {
    const int mtg = mh * 4 + mt;
    const int m = mtg * 16 + n;
#pragma unroll
    for (int kf = 0; kf < 2; ++kf) {
      const float4v* wp = (const float4v*)(W2 + m * CH1 + kf * 32 + quad * 8);
      const float4v lo = wp[0];
      const float4v hi = wp[1];
#pragma unroll
      for (int e = 0; e < 4; ++e) {
        afrag[mt][kf][e]     = (_Float16)lo[e];
        afrag[mt][kf][4 + e] = (_Float16)hi[e];
      }
    }
    bias[mt] = *(const float4v*)(b2 + mtg * 16 + quad * 4);
  }

  __half* hrow = h2 + (size_t)pt * CH2;
#pragma unroll
  for (int mt = 0; mt < 4; ++mt) {
    const int mtg = mh * 4 + mt;
    float4v acc = bias[mt];
    acc = __builtin_amdgcn_mfma_f32_16x16x32_f16(afrag[mt][0], bf0, acc, 0, 0, 0);
    acc = __builtin_amdgcn_mfma_f32_16x16x32_f16(afrag[mt][1], bf1, acc, 0, 0, 0);
    const int p0 = mtg * 16 + quad * 4;
    half2v lo2, hi2;
    lo2[0] = (_Float16)fmaxf(acc[0], 0.f);
    lo2[1] = (_Float16)fmaxf(acc[1], 0.f);
    hi2[0] = (_Float16)fmaxf(acc[2], 0.f);
    hi2[1] = (_Float16)fmaxf(acc[3], 0.f);
    uint2 pk;
    pk.x = __builtin_bit_cast(unsigned, lo2);
    pk.y = __builtin_bit_cast(unsigned, hi2);
    *(uint2*)(hrow + p0) = pk;
  }
}

// ---------------------------------------------------------------------------
// Kernel 2 (R15 = R1 structure + pipelined phase 1 + byte-offset list):
//  - one WAVE per query, 16384 waves (max TLP).
//  - phase 1: 128/iter with early exit (proven best), but iteration i+1's
//    two float4 loads are ISSUED before iteration i's ballot chain -> the
//    L1/L2 load wait overlaps prefix bookkeeping (shorter serial chain).
//  - list[] holds BYTE offsets (idx<<8): kills 16 v_mul_lo in phase-2 setup.
//  - phase 2 / epilogue: R1 layout verbatim.
// ---------------------------------------------------------------------------
__global__ __launch_bounds__(256, 4) void query_kernel(
    const float4v* __restrict__ xyzq,
    const __half* __restrict__ h2,
    float* __restrict__ out) {
  __shared__ int  list[4][NSAMP];   // 1 KB, per-wave private
  __shared__ float fout[4][CH2];    // 2 KB, 4-query output transpose

  const int t = threadIdx.x;
  const int wave = t >> 6;
  const int lane = t & 63;
  const int bid = blockIdx.x;
  const int b = bid & 7;                  // XCD-aware swizzle: XCD owns batch
  const int sbase = (bid >> 3) << 2;      // 4 consecutive queries per block
  const int s = sbase + wave;

  const float4v* xq = xyzq + (size_t)b * NPTS;
  const float4v qv = xq[s];
  const float qx = qv[0], qy = qv[1], qz = qv[2], dqf = qv[3];
  const double dq = (double)qx * qx + (double)qy * qy + (double)qz * qz;
  const unsigned long long lt = (1ull << lane) - 1ull;

  // ---- Phase 1: first NSAMP in-radius hits (ascending), 128/iter,
  //      software-pipelined loads ----
  int count = 0;
  int first = 0;
  float4v nv0 = xq[lane];
  float4v nv1 = xq[64 + lane];
  for (int base = 0; base < NPTS && count < NSAMP; base += 128) {
    const float4v pv0 = nv0;
    const float4v pv1 = nv1;
    const int nb = base + 128;
    if (nb < NPTS) {          // prefetch next iteration's points now
      nv0 = xq[nb + lane];
      nv1 = xq[nb + 64 + lane];
    }

    const float dot0 = fmaf(qz, pv0[2], fmaf(qy, pv0[1], qx * pv0[0]));
    const float dist0 = fmaf(-2.f, dot0, dqf + pv0[3]);
    const float dot1 = fmaf(qz, pv1[2], fmaf(qy, pv1[1], qx * pv1[0]));
    const float dist1 = fmaf(-2.f, dot1, dqf + pv1[3]);
    bool hit0 = !(dist0 > 0.36f);
    bool hit1 = !(dist1 > 0.36f);
    const bool bd = (__builtin_fabsf(dist0 - 0.36f) <= 3e-5f) ||
                    (__builtin_fabsf(dist1 - 0.36f) <= 3e-5f);
    if (__ballot(bd)) {
      // rare exact path: fp64, same evaluation as the np reference
      {
        const double px = pv0[0], py = pv0[1], pz = pv0[2];
        const double dm = px * px + py * py + pz * pz;
        const double dd = (double)qx * px + (double)qy * py + (double)qz * pz;
        hit0 = !((dq + dm - 2.0 * dd) > 0.36);
      }
      {
        const double px = pv1[0], py = pv1[1], pz = pv1[2];
        const double dm = px * px + py * py + pz * pz;
        const double dd = (double)qx * px + (double)qy * py + (double)qz * pz;
        hit1 = !((dq + dm - 2.0 * dd) > 0.36);
      }
    }

    const unsigned long long m0 = __ballot(hit0);
    const unsigned long long m1 = __ballot(hit1);
    const int c0 = __popcll(m0);
    const int c1 = __popcll(m1);

    if (count == 0) {
      first = m0 ? ((base + (int)__builtin_ctzll(m0)) << 8)
                 : (m1 ? ((base + 64 + (int)__builtin_ctzll(m1)) << 8) : first);
    }
    if (hit0) {
      const int pos = count + __popcll(m0 & lt);
      if (pos < NSAMP) list[wave][pos] = (base + lane) << 8;
    }
    if (hit1) {
      const int pos = count + c0 + __popcll(m1 & lt);
      if (pos < NSAMP) list[wave][pos] = (base + 64 + lane) << 8;
    }
    count += c0 + c1;
  }
  // tail fill with first hit (self guarantees count >= 1 on full scan)
  if (count < NSAMP && lane >= count) list[wave][lane] = first;

  __builtin_amdgcn_wave_barrier();
  asm volatile("s_waitcnt lgkmcnt(0)" ::: "memory");
  __builtin_amdgcn_wave_barrier();

  // ---- Phase 2: lane = (rgrp, csl); gather rows rgrp*16..+15, 16-B slice
  //      csl; in-register max tree, then 2 shfl_xor rounds ----
  const int csl  = lane & 15;
  const int rgrp = lane >> 4;
  const char* hb = (const char*)(h2 + (size_t)b * NPTS * CH2) + csl * 16;

  unsigned off[16];
#pragma unroll
  for (int k = 0; k < 4; ++k) {
    const int4 li = *(const int4*)&list[wave][rgrp * 16 + k * 4];
    off[4 * k + 0] = (unsigned)li.x;
    off[4 * k + 1] = (unsigned)li.y;
    off[4 * k + 2] = (unsigned)li.z;
    off[4 * k + 3] = (unsigned)li.w;
  }

  uint4v acc;
  {
    uint4v v[8];
#pragma unroll
    for (int k = 0; k < 8; ++k)
      v[k] = *(const uint4v*)(hb + (size_t)off[k]);
    uint4v a0 = pk4max(pk4max(v[0], v[1]), pk4max(v[2], v[3]));
    uint4v a1 = pk4max(pk4max(v[4], v[5]), pk4max(v[6], v[7]));
    acc = pk4max(a0, a1);
  }
  {
    uint4v v[8];
#pragma unroll
    for (int k = 0; k < 8; ++k)
      v[k] = *(const uint4v*)(hb + (size_t)off[8 + k]);
    uint4v a0 = pk4max(pk4max(v[0], v[1]), pk4max(v[2], v[3]));
    uint4v a1 = pk4max(pk4max(v[4], v[5]), pk4max(v[6], v[7]));
    acc = pk4max(acc, pk4max(a0, a1));
  }

  // cross-lane: combine the 4 row-groups (lanes csl, csl+16, csl+32, csl+48)
  uint4v o;
#pragma unroll
  for (int i = 0; i < 4; ++i)
    o[i] = (unsigned)__shfl_xor((int)acc[i], 16, 64);
  acc = pk4max(acc, o);
#pragma unroll
  for (int i = 0; i < 4; ++i)
    o[i] = (unsigned)__shfl_xor((int)acc[i], 32, 64);
  acc = pk4max(acc, o);

  // lanes 0..15 hold the final 8-channel slice for this query
  if (rgrp == 0) {
    const int c0 = csl * 8;
    fout[wave][c0 + 0] = h2lo(acc[0]);
    fout[wave][c0 + 1] = h2hi(acc[0]);
    fout[wave][c0 + 2] = h2lo(acc[1]);
    fout[wave][c0 + 3] = h2hi(acc[1]);
    fout[wave][c0 + 4] = h2lo(acc[2]);
    fout[wave][c0 + 5] = h2hi(acc[2]);
    fout[wave][c0 + 6] = h2lo(acc[3]);
    fout[wave][c0 + 7] = h2hi(acc[3]);
  }
  __syncthreads();

  // ---- Epilogue: coalesced float4 write per channel line ----
  if (t < CH2) {
    float4v r;
    r[0] = fout[0][t];
    r[1] = fout[1][t];
    r[2] = fout[2][t];
    r[3] = fout[3][t];
    *(float4v*)(out + ((size_t)b * CH2 + t) * NPTS + sbase) = r;
  }
}

// ---------------------------------------------------------------------------
extern "C" void kernel_launch(void* const* d_in, const int* in_sizes, int n_in,
                              void* d_out, int out_size, void* d_ws, size_t ws_size,
                              hipStream_t stream) {
  const float* x  = (const float*)d_in[0];
  const float* W1 = (const float*)d_in[1];
  const float* b1 = (const float*)d_in[2];
  const float* W2 = (const float*)d_in[3];
  const float* b2 = (const float*)d_in[4];
  float* out = (float*)d_out;

  __half*  h2   = (__half*)d_ws;                                     // 4 MB
  float4v* xyzq = (float4v*)((char*)d_ws + (size_t)4 * 1024 * 1024); // 256 KB

  mlp_kernel<<<(BATCH * NPTS) / 32, 256, 0, stream>>>(
      x, W1, b1, W2, b2, h2, xyzq);
  query_kernel<<<(BATCH * NPTS) / 4, 256, 0, stream>>>(xyzq, h2, out);
}